// Round 8
// baseline (398.403 us; speedup 1.0000x reference)
//
#include <hip/hip_runtime.h>
#include <hip/hip_bf16.h>
#include <stdint.h>

typedef unsigned long long u64;
typedef __hip_bfloat16 bf16;
typedef short s8v __attribute__((ext_vector_type(8)));
typedef short s4v __attribute__((ext_vector_type(4)));
typedef float f4v __attribute__((ext_vector_type(4)));

#define B_   16
#define C_   256
#define N_   1024
#define HID_ 512

// fp32 -> bf16 RNE, bit-level
__device__ __forceinline__ unsigned short f2b(float f) {
    unsigned u = __float_as_uint(f);
    unsigned r = (u + 0x7FFFu + ((u >> 16) & 1u)) >> 16;
    return (unsigned short)r;
}
__device__ __forceinline__ float b2f(unsigned short s) {
    return __uint_as_float(((unsigned)s) << 16);
}
// Runtime-dtype input load: bf==1 -> bf16, bf==0 -> fp32.
__device__ __forceinline__ float ldIn(const void* p, long long i, int bf) {
    return bf ? b2f(((const unsigned short*)p)[i]) : ((const float*)p)[i];
}

// ---------------------------------------------------------------------------
// Probe input dtype + fold BN params into per-channel scale/bias.
// ---------------------------------------------------------------------------
__global__ void prep_kernel(const void* xp,
    const void* fc1_b, const void* bn1_g, const void* bn1_b, const void* bn1_m, const void* bn1_v,
    const void* gc_b,  const void* gbn_g, const void* gbn_b, const void* gbn_m, const void* gbn_v,
    const void* bn2_g, const void* bn2_b, const void* bn2_m, const void* bn2_v,
    const void* fc2_b, const void* bn3_g, const void* bn3_b, const void* bn3_m, const void* bn3_v,
    int* flags, float* s1, float* t1, float* Sg, float* Tg, float* s3, float* t3)
{
    __shared__ int sf;
    if (threadIdx.x == 0) {
        const unsigned short* u = (const unsigned short*)xp;
        int cnt = 0;
        for (int i = 0; i < 64; ++i) {
            int e = (u[2 * i] >> 7) & 0xFF;
            cnt += (e >= 87 && e <= 167);
        }
        int f = (cnt >= 48) ? 1 : 0;
        flags[0] = f;
        sf = f;
    }
    __syncthreads();
    int bf = sf;
    int i = threadIdx.x;
    if (i < 256) {
        float g = ldIn(bn1_g, i, bf), bb = ldIn(bn1_b, i, bf);
        float m = ldIn(bn1_m, i, bf), v  = ldIn(bn1_v, i, bf);
        float s = g / sqrtf(v + 1e-5f);
        s1[i] = s;
        t1[i] = (ldIn(fc1_b, i, bf) - m) * s + bb;

        float g3 = ldIn(bn3_g, i, bf), b3 = ldIn(bn3_b, i, bf);
        float m3 = ldIn(bn3_m, i, bf), v3 = ldIn(bn3_v, i, bf);
        float ss3 = g3 / sqrtf(v3 + 1e-5f);
        s3[i] = ss3;
        t3[i] = (ldIn(fc2_b, i, bf) - m3) * ss3 + b3;
    }
    if (i < 512) {
        float gg = ldIn(gbn_g, i, bf), gb = ldIn(gbn_b, i, bf);
        float gm = ldIn(gbn_m, i, bf), gv = ldIn(gbn_v, i, bf);
        float sg = gg / sqrtf(gv + 1e-5f);
        float g2 = ldIn(bn2_g, i, bf), b2 = ldIn(bn2_b, i, bf);
        float m2 = ldIn(bn2_m, i, bf), v2 = ldIn(bn2_v, i, bf);
        float s2 = g2 / sqrtf(v2 + 1e-5f);
        Sg[i] = sg * s2;
        Tg[i] = ((ldIn(gc_b, i, bf) - gm) * sg + gb - m2) * s2 + b2;
    }
}

// ---------------------------------------------------------------------------
// Weights: gc/fc2 -> bf16 (fc1 stays fp32-VALU, reads input directly).
// items = 65536 + 262144 + 131072 = 458752 = 1792 * 256
// ---------------------------------------------------------------------------
__global__ __launch_bounds__(256)
void cast_weights(const void* w1, const void* wg, const void* w2,
                  short* W1b, short* Wgb, short* W2b, const int* flags)
{
    int inf = flags[0];
    int i = blockIdx.x * 256 + threadIdx.x;
    if (i < 65536) {
        W1b[i] = (short)f2b(ldIn(w1, i, inf));
    } else if (i < 65536 + 262144) {
        int j = i - 65536;
        Wgb[j] = (short)f2b(ldIn(wg, j, inf));
    } else {
        int j = i - 327680;
        W2b[j] = (short)f2b(ldIn(w2, j, inf));
    }
}

// ---------------------------------------------------------------------------
// fc1 (VALU, fp32 — R6 known-good): Ft[b][n][c] = s1[c]*sum_k w[c][k]*x[b][k][n] + t1[c]
// 64x64 tile, 4x4/thread. Node-major fp32 output.
// ---------------------------------------------------------------------------
__global__ __launch_bounds__(256)
void fc1_valu(const void* __restrict__ Aw, const void* __restrict__ Bx,
              float* __restrict__ Ft, const float* __restrict__ s1,
              const float* __restrict__ t1, const int* __restrict__ flags)
{
    __shared__ float As[16][68];
    __shared__ float Bs[16][68];

    int inf = flags[0];
    int b  = blockIdx.z;
    int o0 = blockIdx.y * 64, n0 = blockIdx.x * 64;
    int t  = threadIdx.x;
    int tn = t & 15, to = t >> 4;
    long long bbase = (long long)b * C_ * N_;

    float acc[4][4] = {};

    for (int k0 = 0; k0 < C_; k0 += 16) {
        {
            int l = t * 4;
            int ao = l >> 4, ak = l & 15;
            long long ai = (long long)(o0 + ao) * C_ + k0 + ak;
            As[ak + 0][ao] = ldIn(Aw, ai + 0, inf);
            As[ak + 1][ao] = ldIn(Aw, ai + 1, inf);
            As[ak + 2][ao] = ldIn(Aw, ai + 2, inf);
            As[ak + 3][ao] = ldIn(Aw, ai + 3, inf);
        }
        {
            int l = t * 4;
            int bk = l >> 6, bn = l & 63;
            long long bi = bbase + (long long)(k0 + bk) * N_ + n0 + bn;
            Bs[bk][bn + 0] = ldIn(Bx, bi + 0, inf);
            Bs[bk][bn + 1] = ldIn(Bx, bi + 1, inf);
            Bs[bk][bn + 2] = ldIn(Bx, bi + 2, inf);
            Bs[bk][bn + 3] = ldIn(Bx, bi + 3, inf);
        }
        __syncthreads();
        #pragma unroll
        for (int k = 0; k < 16; ++k) {
            float av[4], bv[4];
            #pragma unroll
            for (int i = 0; i < 4; ++i) av[i] = As[k][to * 4 + i];
            #pragma unroll
            for (int j = 0; j < 4; ++j) bv[j] = Bs[k][tn * 4 + j];
            #pragma unroll
            for (int i = 0; i < 4; ++i)
                #pragma unroll
                for (int j = 0; j < 4; ++j) acc[i][j] += av[i] * bv[j];
        }
        __syncthreads();
    }

    #pragma unroll
    for (int i = 0; i < 4; ++i) {
        int o = o0 + to * 4 + i;
        float s = s1[o], tt = t1[o];
        #pragma unroll
        for (int j = 0; j < 4; ++j) {
            int n = n0 + tn * 4 + j;
            Ft[((long long)(b << 10) + n) * C_ + o] = acc[i][j] * s + tt;
        }
    }
}

// ---------------------------------------------------------------------------
// prep_F: Ft fp32 [n][c] -> Fhi/Flo bf16 split + x2[n] = sum_c Ft^2
// grid (N/4, B), block 256 = 4 waves; wave per n, lane covers 4 c.
// ---------------------------------------------------------------------------
__global__ __launch_bounds__(256)
void prep_F(const float* __restrict__ Ft, short* __restrict__ Fhi,
            short* __restrict__ Flo, float* __restrict__ x2)
{
    int t = threadIdx.x;
    int wv = t >> 6, lane = t & 63;
    int n = blockIdx.x * 4 + wv;
    int b = blockIdx.y;
    long long base = ((long long)(b << 10) + n) * C_ + lane * 4;
    f4v f = *(const f4v*)(Ft + base);

    s4v hi, lo;
    #pragma unroll
    for (int r = 0; r < 4; ++r) {
        unsigned short h = f2b(f[r]);
        hi[r] = (short)h;
        lo[r] = (short)f2b(f[r] - b2f(h));
    }
    *(s4v*)(Fhi + base) = hi;
    *(s4v*)(Flo + base) = lo;

    float ss = f[0]*f[0] + f[1]*f[1] + f[2]*f[2] + f[3]*f[3];
    #pragma unroll
    for (int s = 32; s >= 1; s >>= 1) ss += __shfl_xor(ss, s, 64);
    if (lane == 0) x2[(b << 10) + n] = ss;
}

// ---------------------------------------------------------------------------
// Fused gram + top-9. Block: 128 q-rows x one m-half (512), m-loop 8x64.
// 4-pass hi/lo MFMA -> D-tile in LDS -> per-thread ladder top-9 -> merges.
// Partial (per m-half) sorted lists -> Part[b][q][mh][9] (u64 keys).
// grid (8 qtiles, 2 mhalves, 16 b) = 256 blocks.
// ---------------------------------------------------------------------------
__global__ __launch_bounds__(256)
void gram_topk(const short* __restrict__ Fhi, const short* __restrict__ Flo,
               const float* __restrict__ x2, u64* __restrict__ Part)
{
    __shared__ short Ah[128][40], Al[128][40];
    __shared__ short Bh[64][40],  Bl[64][40];
    __shared__ __align__(16) float Dt[128][66];   // overlaid by mrg after scans
    u64* mrgp = (u64*)&Dt[0][0];                  // [128][2][9] = 18432 B

    int t = threadIdx.x;
    int q0 = blockIdx.x * 128, mh = blockIdx.y, b = blockIdx.z;
    int mbase = mh * 512;
    int wv = t >> 6, ln = t & 15, quad = (t >> 4) & 3;
    int wq = (wv & 1) * 64, wm = (wv >> 1) * 32;

    u64 l[9];
    #pragma unroll
    for (int i = 0; i < 9; ++i) l[i] = ~0ULL;

    for (int mt = 0; mt < 8; ++mt) {
        int m0 = mbase + mt * 64;
        f4v acc[4][2];
        #pragma unroll
        for (int i = 0; i < 4; ++i)
            #pragma unroll
            for (int j = 0; j < 2; ++j) acc[i][j] = 0.f;

        for (int kc = 0; kc < 8; ++kc) {
            __syncthreads();
            #pragma unroll
            for (int s = 0; s < 2; ++s) {
                int sid = t + s * 256;
                int row = sid >> 2, seg = sid & 3;
                long long ga = ((long long)((b << 10) + q0 + row)) * C_ + kc * 32 + seg * 8;
                *(s8v*)&Ah[row][seg * 8] = *(const s8v*)(Fhi + ga);
                *(s8v*)&Al[row][seg * 8] = *(const s8v*)(Flo + ga);
            }
            {
                int row = t >> 2, seg = t & 3;
                long long gb = ((long long)((b << 10) + m0 + row)) * C_ + kc * 32 + seg * 8;
                *(s8v*)&Bh[row][seg * 8] = *(const s8v*)(Fhi + gb);
                *(s8v*)&Bl[row][seg * 8] = *(const s8v*)(Flo + gb);
            }
            __syncthreads();
            s8v ah[4], al[4], bh[2], bl[2];
            #pragma unroll
            for (int i = 0; i < 4; ++i) {
                ah[i] = *(s8v*)&Ah[wq + i * 16 + ln][quad * 8];
                al[i] = *(s8v*)&Al[wq + i * 16 + ln][quad * 8];
            }
            #pragma unroll
            for (int j = 0; j < 2; ++j) {
                bh[j] = *(s8v*)&Bh[wm + j * 16 + ln][quad * 8];
                bl[j] = *(s8v*)&Bl[wm + j * 16 + ln][quad * 8];
            }
            #pragma unroll
            for (int i = 0; i < 4; ++i)
                #pragma unroll
                for (int j = 0; j < 2; ++j) {
                    acc[i][j] = __builtin_amdgcn_mfma_f32_16x16x32_bf16(ah[i], bh[j], acc[i][j], 0, 0, 0);
                    acc[i][j] = __builtin_amdgcn_mfma_f32_16x16x32_bf16(ah[i], bl[j], acc[i][j], 0, 0, 0);
                    acc[i][j] = __builtin_amdgcn_mfma_f32_16x16x32_bf16(al[i], bh[j], acc[i][j], 0, 0, 0);
                    acc[i][j] = __builtin_amdgcn_mfma_f32_16x16x32_bf16(al[i], bl[j], acc[i][j], 0, 0, 0);
                }
        }
        __syncthreads();
        // epilogue: D-tile to LDS
        #pragma unroll
        for (int j = 0; j < 2; ++j) {
            int Cc = wm + j * 16 + ln;
            float xm = x2[(b << 10) + m0 + Cc];
            #pragma unroll
            for (int i = 0; i < 4; ++i) {
                #pragma unroll
                for (int r = 0; r < 4; ++r)
                    Dt[wq + i * 16 + quad * 4 + r][Cc] = xm - 2.f * acc[i][j][r];
            }
        }
        __syncthreads();
        // scan: thread owns (row, 32-col part)
        {
            int row = t >> 1, part = t & 1;
            #pragma unroll
            for (int c = 0; c < 32; ++c) {
                int cc = part * 32 + c;
                float d = Dt[row][cc];
                int m = m0 + cc;
                unsigned u = __float_as_uint(d);
                u = (u & 0x80000000u) ? ~u : (u | 0x80000000u);
                u64 key = ((u64)u << 32) | (unsigned)m;
                if (key < l[8]) {
                    u64 x = key;
                    #pragma unroll
                    for (int jj = 0; jj < 9; ++jj) {
                        u64 lo2 = l[jj] < x ? l[jj] : x;
                        u64 hi2 = l[jj] < x ? x : l[jj];
                        l[jj] = lo2; x = hi2;
                    }
                }
            }
        }
    }

    __syncthreads();
    {
        int row = t >> 1, part = t & 1;
        #pragma unroll
        for (int k = 0; k < 9; ++k) mrgp[(row * 2 + part) * 9 + k] = l[k];
    }
    __syncthreads();
    if (t < 128) {
        const u64* LA = &mrgp[(t * 2 + 0) * 9];
        const u64* LB = &mrgp[(t * 2 + 1) * 9];
        int ia = 0, ib = 0;
        u64* P = Part + (((long long)((b << 10) + q0 + t)) * 2 + mh) * 9;
        #pragma unroll
        for (int k = 0; k < 9; ++k) {
            u64 va = LA[ia], vb = LB[ib];
            bool ta = va < vb;
            P[k] = ta ? va : vb;
            ia += ta; ib += !ta;
        }
    }
}

// ---------------------------------------------------------------------------
// Merge the two m-half sorted lists -> final 9 neighbor indices per row.
// ---------------------------------------------------------------------------
__global__ __launch_bounds__(256)
void merge_final(const u64* __restrict__ Part, int* __restrict__ ix)
{
    int row = blockIdx.x * 256 + threadIdx.x;   // 0..16383
    const u64* LA = Part + (long long)row * 18;
    const u64* LB = LA + 9;
    int ia = 0, ib = 0;
    #pragma unroll
    for (int k = 0; k < 9; ++k) {
        u64 va = LA[ia], vb = LB[ib];
        bool ta = va < vb;
        ix[row * 9 + k] = (int)((ta ? va : vb) & 0xFFFFFFFFu);
        ia += ta; ib += !ta;
    }
}

// ---------------------------------------------------------------------------
// build_Mt (R6 known-good, reads Ft fp32):
// Mt[b][n][2c]=bf16(Ft); Mt[b][n][2c+1]=bf16(max_k Ft[idx]-Ft)
// ---------------------------------------------------------------------------
__global__ __launch_bounds__(256)
void build_Mt(const float* __restrict__ Ft, const int* __restrict__ idx,
              short* __restrict__ Mt)
{
    int t = threadIdx.x;
    int wv = t >> 6, lane = t & 63;
    int n = blockIdx.x * 4 + wv;
    int b = blockIdx.y;
    int c0 = lane * 4;
    long long nb = (long long)(b << 10) + n;

    f4v f = *(const f4v*)(Ft + nb * C_ + c0);
    const int* id = idx + nb * 9;
    f4v mx = {-3.4e38f, -3.4e38f, -3.4e38f, -3.4e38f};
    #pragma unroll
    for (int k = 0; k < 9; ++k) {
        f4v g = *(const f4v*)(Ft + ((long long)(b << 10) + id[k]) * C_ + c0);
        mx[0] = fmaxf(mx[0], g[0]); mx[1] = fmaxf(mx[1], g[1]);
        mx[2] = fmaxf(mx[2], g[2]); mx[3] = fmaxf(mx[3], g[3]);
    }
    s8v m8;
    #pragma unroll
    for (int r = 0; r < 4; ++r) {
        m8[2 * r]     = (short)f2b(f[r]);
        m8[2 * r + 1] = (short)f2b(mx[r] - f[r]);
    }
    *(s8v*)(Mt + nb * (2 * C_) + 2 * c0) = m8;
}

// ---------------------------------------------------------------------------
// MFMA GEMM (R6 known-good): acc[o][n] = sum_k A[o][k] * Bm[b][n][k]
// EPI 0: gelu(acc*s+t) -> bf16 Gt[b][n][Odim]
// EPI 1: acc*s+t + resid -> fp32 out[b][o][1024]
// ---------------------------------------------------------------------------
template<int EPI>
__global__ __launch_bounds__(256)
void mfma_gemm(const short* __restrict__ A, const short* __restrict__ Bm,
               void* __restrict__ Out, const float* __restrict__ scale,
               const float* __restrict__ bias, const void* __restrict__ resid,
               const int* __restrict__ flags, int K, int Odim)
{
    __shared__ short As[128][40];
    __shared__ short Bs[128][40];

    int t = threadIdx.x, b = blockIdx.z;
    int n0 = blockIdx.x * 128, o0 = blockIdx.y * 128;
    int wv = t >> 6, ln = t & 15, quad = (t >> 4) & 3;
    int wo = (wv & 1) * 64, wn = (wv >> 1) * 64;

    f4v acc[4][4];
    #pragma unroll
    for (int i = 0; i < 4; ++i)
        #pragma unroll
        for (int j = 0; j < 4; ++j) acc[i][j] = 0.f;

    const short* Ab = A + (long long)o0 * K;
    const short* Bb = Bm + ((long long)(b << 10) + n0) * K;

    for (int k0 = 0; k0 < K; k0 += 32) {
        __syncthreads();
        #pragma unroll
        for (int s = 0; s < 2; ++s) {
            int sid = t + s * 256;
            int row = sid >> 2, seg = sid & 3;
            *(s8v*)&As[row][seg * 8] = *(const s8v*)(Ab + (long long)row * K + k0 + seg * 8);
            *(s8v*)&Bs[row][seg * 8] = *(const s8v*)(Bb + (long long)row * K + k0 + seg * 8);
        }
        __syncthreads();
        s8v a[4], bf[4];
        #pragma unroll
        for (int i = 0; i < 4; ++i) a[i]  = *(s8v*)&As[wo + i * 16 + ln][quad * 8];
        #pragma unroll
        for (int j = 0; j < 4; ++j) bf[j] = *(s8v*)&Bs[wn + j * 16 + ln][quad * 8];
        #pragma unroll
        for (int i = 0; i < 4; ++i)
            #pragma unroll
            for (int j = 0; j < 4; ++j)
                acc[i][j] = __builtin_amdgcn_mfma_f32_16x16x32_bf16(a[i], bf[j], acc[i][j], 0, 0, 0);
    }

    int inf = flags[0];
    #pragma unroll
    for (int i = 0; i < 4; ++i) {
        int ob = o0 + wo + i * 16 + quad * 4;
        #pragma unroll
        for (int j = 0; j < 4; ++j) {
            int n = n0 + wn + j * 16 + ln;
            f4v v = acc[i][j];
            if (EPI == 0) {
                s4v g;
                #pragma unroll
                for (int r = 0; r < 4; ++r) {
                    float val = v[r] * scale[ob + r] + bias[ob + r];
                    val = 0.5f * val * (1.0f + erff(val * 0.70710678118654752f));
                    g[r] = (short)f2b(val);
                }
                *(s4v*)((short*)Out + ((long long)(b << 10) + n) * Odim + ob) = g;
            } else {
                #pragma unroll
                for (int r = 0; r < 4; ++r) {
                    int o = ob + r;
                    long long oi = ((long long)b * Odim + o) * N_ + n;
                    ((float*)Out)[oi] = v[r] * scale[o] + bias[o] + ldIn(resid, oi, inf);
                }
            }
        }
    }
}

// ---------------------------------------------------------------------------
extern "C" void kernel_launch(void* const* d_in, const int* in_sizes, int n_in,
                              void* d_out, int out_size, void* d_ws, size_t ws_size,
                              hipStream_t stream)
{
    const void* p[23];
    if (n_in >= 23 && in_sizes[0] != 4194304 && in_sizes[22] == 4194304) {
        const int amap[23] = {
            22, 13, 12, 1, 0, 2, 3,
            21, 20, 17, 16, 18, 19,
            5, 4, 6, 7,
            15, 14, 9, 8, 10, 11 };
        for (int i = 0; i < 23; ++i) p[i] = d_in[amap[i]];
    } else {
        for (int i = 0; i < 23; ++i) p[i] = d_in[i];
    }

    const void* x     = p[0];
    const void* fc1_w = p[1];
    const void* fc1_b = p[2];
    const void* bn1_g = p[3];
    const void* bn1_b = p[4];
    const void* bn1_m = p[5];
    const void* bn1_v = p[6];
    const void* gc_w  = p[7];
    const void* gc_b  = p[8];
    const void* gbn_g = p[9];
    const void* gbn_b = p[10];
    const void* gbn_m = p[11];
    const void* gbn_v = p[12];
    const void* bn2_g = p[13];
    const void* bn2_b = p[14];
    const void* bn2_m = p[15];
    const void* bn2_v = p[16];
    const void* fc2_w = p[17];
    const void* fc2_b = p[18];
    const void* bn3_g = p[19];
    const void* bn3_b = p[20];
    const void* bn3_m = p[21];
    const void* bn3_v = p[22];

    char* ws = (char*)d_ws;
    size_t off = 0;
    int*   flags = (int*)ws;
    float* s1 = (float*)(ws + 256);
    float* t1 = s1 + 256;
    float* s3 = t1 + 256;
    float* t3 = s3 + 256;
    float* Sg = t3 + 256;
    float* Tg = Sg + 512;
    off = 16384;
    int*   ixAll = (int*)(ws + off);  off += (size_t)B_ * N_ * 9 * 4;       // 576 KiB
    short* W1b   = (short*)(ws + off); off += (size_t)C_ * C_ * 2;          // 128 KiB
    short* Wgb   = (short*)(ws + off); off += (size_t)HID_ * 2 * C_ * 2;    // 512 KiB
    short* W2b   = (short*)(ws + off); off += (size_t)C_ * HID_ * 2;        // 256 KiB
    float* Ft    = (float*)(ws + off); off += (size_t)B_ * N_ * C_ * 4;     // 16 MiB
    short* Fhi   = (short*)(ws + off); off += (size_t)B_ * N_ * C_ * 2;     // 8 MiB
    short* Flo   = (short*)(ws + off); off += (size_t)B_ * N_ * C_ * 2;     // 8 MiB
    float* x2    = (float*)(ws + off); off += (size_t)B_ * N_ * 4;          // 64 KiB
    u64*   Part  = (u64*)  (ws + off); off += (size_t)B_ * N_ * 2 * 9 * 8;  // 2.25 MiB
    short* Mt    = (short*)(ws + off); off += (size_t)B_ * N_ * 2 * C_ * 2; // 16 MiB
    short* Gt    = (short*)(ws + off); off += (size_t)B_ * N_ * HID_ * 2;   // 16 MiB

    prep_kernel<<<1, 512, 0, stream>>>(x,
        fc1_b, bn1_g, bn1_b, bn1_m, bn1_v,
        gc_b, gbn_g, gbn_b, gbn_m, gbn_v,
        bn2_g, bn2_b, bn2_m, bn2_v,
        fc2_b, bn3_g, bn3_b, bn3_m, bn3_v,
        flags, s1, t1, Sg, Tg, s3, t3);

    cast_weights<<<1792, 256, 0, stream>>>(fc1_w, gc_w, fc2_w,
                                           W1b, Wgb, W2b, flags);

    // fc1 + BN1 -> Ft fp32 [b][n][c]  (R6 known-good path)
    fc1_valu<<<dim3(16, 4, B_), 256, 0, stream>>>(fc1_w, x, Ft, s1, t1, flags);

    // split + x2 from fp32 Ft  (R6 known-good path)
    prep_F<<<dim3(N_ / 4, B_), 256, 0, stream>>>(Ft, Fhi, Flo, x2);

    // fused gram + top-9 (NEW — the single variable under test)
    gram_topk<<<dim3(8, 2, 16), 256, 0, stream>>>(Fhi, Flo, x2, Part);
    merge_final<<<64, 256, 0, stream>>>(Part, ixAll);

    // Mt from fp32 Ft (R6 known-good path)
    build_Mt<<<dim3(256, 16), 256, 0, stream>>>(Ft, ixAll, Mt);

    mfma_gemm<0><<<dim3(8, 4, 16), 256, 0, stream>>>(
        Wgb, Mt, Gt, Sg, Tg, nullptr, flags, 2 * C_, HID_);

    mfma_gemm<1><<<dim3(8, 2, 16), 256, 0, stream>>>(
        W2b, Gt, d_out, s3, t3, x, flags, HID_, C_);
}

// Round 9
// 325.970 us; speedup vs baseline: 1.2222x; 1.2222x over previous
//
#include <hip/hip_runtime.h>
#include <hip/hip_bf16.h>
#include <stdint.h>

typedef unsigned long long u64;
typedef __hip_bfloat16 bf16;
typedef short s8v __attribute__((ext_vector_type(8)));
typedef short s4v __attribute__((ext_vector_type(4)));
typedef float f4v __attribute__((ext_vector_type(4)));

#define B_   16
#define C_   256
#define N_   1024
#define HID_ 512

// fp32 -> bf16 RNE, bit-level
__device__ __forceinline__ unsigned short f2b(float f) {
    unsigned u = __float_as_uint(f);
    unsigned r = (u + 0x7FFFu + ((u >> 16) & 1u)) >> 16;
    return (unsigned short)r;
}
__device__ __forceinline__ float b2f(unsigned short s) {
    return __uint_as_float(((unsigned)s) << 16);
}
// Runtime-dtype input load: bf==1 -> bf16, bf==0 -> fp32.
__device__ __forceinline__ float ldIn(const void* p, long long i, int bf) {
    return bf ? b2f(((const unsigned short*)p)[i]) : ((const float*)p)[i];
}

// ---------------------------------------------------------------------------
// Probe input dtype + fold BN params into per-channel scale/bias.
// ---------------------------------------------------------------------------
__global__ void prep_kernel(const void* xp,
    const void* fc1_b, const void* bn1_g, const void* bn1_b, const void* bn1_m, const void* bn1_v,
    const void* gc_b,  const void* gbn_g, const void* gbn_b, const void* gbn_m, const void* gbn_v,
    const void* bn2_g, const void* bn2_b, const void* bn2_m, const void* bn2_v,
    const void* fc2_b, const void* bn3_g, const void* bn3_b, const void* bn3_m, const void* bn3_v,
    int* flags, float* s1, float* t1, float* Sg, float* Tg, float* s3, float* t3)
{
    __shared__ int sf;
    if (threadIdx.x == 0) {
        const unsigned short* u = (const unsigned short*)xp;
        int cnt = 0;
        for (int i = 0; i < 64; ++i) {
            int e = (u[2 * i] >> 7) & 0xFF;
            cnt += (e >= 87 && e <= 167);
        }
        int f = (cnt >= 48) ? 1 : 0;
        flags[0] = f;
        sf = f;
    }
    __syncthreads();
    int bf = sf;
    int i = threadIdx.x;
    if (i < 256) {
        float g = ldIn(bn1_g, i, bf), bb = ldIn(bn1_b, i, bf);
        float m = ldIn(bn1_m, i, bf), v  = ldIn(bn1_v, i, bf);
        float s = g / sqrtf(v + 1e-5f);
        s1[i] = s;
        t1[i] = (ldIn(fc1_b, i, bf) - m) * s + bb;

        float g3 = ldIn(bn3_g, i, bf), b3 = ldIn(bn3_b, i, bf);
        float m3 = ldIn(bn3_m, i, bf), v3 = ldIn(bn3_v, i, bf);
        float ss3 = g3 / sqrtf(v3 + 1e-5f);
        s3[i] = ss3;
        t3[i] = (ldIn(fc2_b, i, bf) - m3) * ss3 + b3;
    }
    if (i < 512) {
        float gg = ldIn(gbn_g, i, bf), gb = ldIn(gbn_b, i, bf);
        float gm = ldIn(gbn_m, i, bf), gv = ldIn(gbn_v, i, bf);
        float sg = gg / sqrtf(gv + 1e-5f);
        float g2 = ldIn(bn2_g, i, bf), b2 = ldIn(bn2_b, i, bf);
        float m2 = ldIn(bn2_m, i, bf), v2 = ldIn(bn2_v, i, bf);
        float s2 = g2 / sqrtf(v2 + 1e-5f);
        Sg[i] = sg * s2;
        Tg[i] = ((ldIn(gc_b, i, bf) - gm) * sg + gb - m2) * s2 + b2;
    }
}

// ---------------------------------------------------------------------------
// Weights: gc/fc2 -> bf16 (fc1 stays fp32-VALU).
// ---------------------------------------------------------------------------
__global__ __launch_bounds__(256)
void cast_weights(const void* w1, const void* wg, const void* w2,
                  short* W1b, short* Wgb, short* W2b, const int* flags)
{
    int inf = flags[0];
    int i = blockIdx.x * 256 + threadIdx.x;
    if (i < 65536) {
        W1b[i] = (short)f2b(ldIn(w1, i, inf));
    } else if (i < 65536 + 262144) {
        int j = i - 65536;
        Wgb[j] = (short)f2b(ldIn(wg, j, inf));
    } else {
        int j = i - 327680;
        W2b[j] = (short)f2b(ldIn(w2, j, inf));
    }
}

// ---------------------------------------------------------------------------
// fc1 (VALU, fp32 — known-good): Ft[b][n][c] = s1[c]*sum_k w[c][k]*x[b][k][n] + t1[c]
// ---------------------------------------------------------------------------
__global__ __launch_bounds__(256)
void fc1_valu(const void* __restrict__ Aw, const void* __restrict__ Bx,
              float* __restrict__ Ft, const float* __restrict__ s1,
              const float* __restrict__ t1, const int* __restrict__ flags)
{
    __shared__ float As[16][68];
    __shared__ float Bs[16][68];

    int inf = flags[0];
    int b  = blockIdx.z;
    int o0 = blockIdx.y * 64, n0 = blockIdx.x * 64;
    int t  = threadIdx.x;
    int tn = t & 15, to = t >> 4;
    long long bbase = (long long)b * C_ * N_;

    float acc[4][4] = {};

    for (int k0 = 0; k0 < C_; k0 += 16) {
        {
            int l = t * 4;
            int ao = l >> 4, ak = l & 15;
            long long ai = (long long)(o0 + ao) * C_ + k0 + ak;
            As[ak + 0][ao] = ldIn(Aw, ai + 0, inf);
            As[ak + 1][ao] = ldIn(Aw, ai + 1, inf);
            As[ak + 2][ao] = ldIn(Aw, ai + 2, inf);
            As[ak + 3][ao] = ldIn(Aw, ai + 3, inf);
        }
        {
            int l = t * 4;
            int bk = l >> 6, bn = l & 63;
            long long bi = bbase + (long long)(k0 + bk) * N_ + n0 + bn;
            Bs[bk][bn + 0] = ldIn(Bx, bi + 0, inf);
            Bs[bk][bn + 1] = ldIn(Bx, bi + 1, inf);
            Bs[bk][bn + 2] = ldIn(Bx, bi + 2, inf);
            Bs[bk][bn + 3] = ldIn(Bx, bi + 3, inf);
        }
        __syncthreads();
        #pragma unroll
        for (int k = 0; k < 16; ++k) {
            float av[4], bv[4];
            #pragma unroll
            for (int i = 0; i < 4; ++i) av[i] = As[k][to * 4 + i];
            #pragma unroll
            for (int j = 0; j < 4; ++j) bv[j] = Bs[k][tn * 4 + j];
            #pragma unroll
            for (int i = 0; i < 4; ++i)
                #pragma unroll
                for (int j = 0; j < 4; ++j) acc[i][j] += av[i] * bv[j];
        }
        __syncthreads();
    }

    #pragma unroll
    for (int i = 0; i < 4; ++i) {
        int o = o0 + to * 4 + i;
        float s = s1[o], tt = t1[o];
        #pragma unroll
        for (int j = 0; j < 4; ++j) {
            int n = n0 + tn * 4 + j;
            Ft[((long long)(b << 10) + n) * C_ + o] = acc[i][j] * s + tt;
        }
    }
}

// ---------------------------------------------------------------------------
// prep_F: Ft fp32 [n][c] -> Fhi/Flo bf16 split + x2[n] = sum_c Ft^2
// ---------------------------------------------------------------------------
__global__ __launch_bounds__(256)
void prep_F(const float* __restrict__ Ft, short* __restrict__ Fhi,
            short* __restrict__ Flo, float* __restrict__ x2)
{
    int t = threadIdx.x;
    int wv = t >> 6, lane = t & 63;
    int n = blockIdx.x * 4 + wv;
    int b = blockIdx.y;
    long long base = ((long long)(b << 10) + n) * C_ + lane * 4;
    f4v f = *(const f4v*)(Ft + base);

    s4v hi, lo;
    #pragma unroll
    for (int r = 0; r < 4; ++r) {
        unsigned short h = f2b(f[r]);
        hi[r] = (short)h;
        lo[r] = (short)f2b(f[r] - b2f(h));
    }
    *(s4v*)(Fhi + base) = hi;
    *(s4v*)(Flo + base) = lo;

    float ss = f[0]*f[0] + f[1]*f[1] + f[2]*f[2] + f[3]*f[3];
    #pragma unroll
    for (int s = 32; s >= 1; s >>= 1) ss += __shfl_xor(ss, s, 64);
    if (lane == 0) x2[(b << 10) + n] = ss;
}

// ---------------------------------------------------------------------------
// Fused gram + top-9 v2 (occupancy-tuned).
// Block: 64 q-rows x 256 m (m-quarter). grid (16 q, 4 mq, 16 b) = 1024 blocks.
// LDS 37.6 KB -> 4 blocks/CU. m-loop 4x64; per mt: 4-pass hi/lo MFMA
// (per wave 32q x 32m, 2x2 frags) -> Dt[64][67] (odd stride: 2-way banks)
// -> per-thread (row, 16-col) ladder scan. In-block 4->2->1 merges (LDS
// overlays) -> Part[row][mq][9].
// ---------------------------------------------------------------------------
__global__ __launch_bounds__(256)
void gram_topk(const short* __restrict__ Fhi, const short* __restrict__ Flo,
               const float* __restrict__ x2, u64* __restrict__ Part)
{
    __shared__ __align__(16) char ldsbuf[37632];
    short* Ah = (short*)(ldsbuf);            // [64][40] 5120 B
    short* Al = (short*)(ldsbuf + 5120);
    short* Bh = (short*)(ldsbuf + 10240);
    short* Bl = (short*)(ldsbuf + 15360);
    float* Dt = (float*)(ldsbuf + 20480);    // [64][67] 17152 B
    u64*   mrg  = (u64*)(ldsbuf);            // overlay A+B: 64*4*9*8 = 18432 B
    u64*   mrg2 = (u64*)(ldsbuf + 20480);    // overlay Dt: 64*2*9*8 = 9216 B

    int t = threadIdx.x;
    int q0 = blockIdx.x * 64, mq = blockIdx.y, b = blockIdx.z;
    int wv = t >> 6, ln = t & 15, quad = (t >> 4) & 3;
    int wq = (wv & 1) * 32, wm = (wv >> 1) * 32;

    u64 l[9];
    #pragma unroll
    for (int i = 0; i < 9; ++i) l[i] = ~0ULL;

    for (int mt = 0; mt < 4; ++mt) {
        int m0 = mq * 256 + mt * 64;
        f4v acc[2][2];
        #pragma unroll
        for (int i = 0; i < 2; ++i)
            #pragma unroll
            for (int j = 0; j < 2; ++j) acc[i][j] = 0.f;

        for (int kc = 0; kc < 8; ++kc) {
            __syncthreads();
            {
                int row = t >> 2, seg = t & 3;
                long long ga = ((long long)((b << 10) + q0 + row)) * C_ + kc * 32 + seg * 8;
                *(s8v*)&Ah[row * 40 + seg * 8] = *(const s8v*)(Fhi + ga);
                *(s8v*)&Al[row * 40 + seg * 8] = *(const s8v*)(Flo + ga);
                long long gb = ((long long)((b << 10) + m0 + row)) * C_ + kc * 32 + seg * 8;
                *(s8v*)&Bh[row * 40 + seg * 8] = *(const s8v*)(Fhi + gb);
                *(s8v*)&Bl[row * 40 + seg * 8] = *(const s8v*)(Flo + gb);
            }
            __syncthreads();
            s8v ah[2], al[2], bh[2], bl[2];
            #pragma unroll
            for (int i = 0; i < 2; ++i) {
                ah[i] = *(s8v*)&Ah[(wq + i * 16 + ln) * 40 + quad * 8];
                al[i] = *(s8v*)&Al[(wq + i * 16 + ln) * 40 + quad * 8];
            }
            #pragma unroll
            for (int j = 0; j < 2; ++j) {
                bh[j] = *(s8v*)&Bh[(wm + j * 16 + ln) * 40 + quad * 8];
                bl[j] = *(s8v*)&Bl[(wm + j * 16 + ln) * 40 + quad * 8];
            }
            #pragma unroll
            for (int i = 0; i < 2; ++i)
                #pragma unroll
                for (int j = 0; j < 2; ++j) {
                    acc[i][j] = __builtin_amdgcn_mfma_f32_16x16x32_bf16(ah[i], bh[j], acc[i][j], 0, 0, 0);
                    acc[i][j] = __builtin_amdgcn_mfma_f32_16x16x32_bf16(ah[i], bl[j], acc[i][j], 0, 0, 0);
                    acc[i][j] = __builtin_amdgcn_mfma_f32_16x16x32_bf16(al[i], bh[j], acc[i][j], 0, 0, 0);
                    acc[i][j] = __builtin_amdgcn_mfma_f32_16x16x32_bf16(al[i], bl[j], acc[i][j], 0, 0, 0);
                }
        }
        __syncthreads();   // prior scan done before Dt overwrite
        #pragma unroll
        for (int j = 0; j < 2; ++j) {
            int ml = wm + j * 16 + ln;
            float xm = x2[(b << 10) + m0 + ml];
            #pragma unroll
            for (int i = 0; i < 2; ++i) {
                #pragma unroll
                for (int r = 0; r < 4; ++r)
                    Dt[(wq + i * 16 + quad * 4 + r) * 67 + ml] = xm - 2.f * acc[i][j][r];
            }
        }
        __syncthreads();
        {   // scan: thread owns (row = t>>2, 16-col part = t&3)
            int row = t >> 2, part = t & 3;
            #pragma unroll
            for (int c = 0; c < 16; ++c) {
                int cc = part * 16 + c;
                float d = Dt[row * 67 + cc];
                int m = m0 + cc;
                unsigned u = __float_as_uint(d);
                u = (u & 0x80000000u) ? ~u : (u | 0x80000000u);
                u64 key = ((u64)u << 32) | (unsigned)m;
                if (key < l[8]) {
                    u64 x = key;
                    #pragma unroll
                    for (int jj = 0; jj < 9; ++jj) {
                        u64 lo2 = l[jj] < x ? l[jj] : x;
                        u64 hi2 = l[jj] < x ? x : l[jj];
                        l[jj] = lo2; x = hi2;
                    }
                }
            }
        }
    }

    __syncthreads();   // scans done; safe to overlay A/B with mrg
    {
        int row = t >> 2, part = t & 3;
        #pragma unroll
        for (int k = 0; k < 9; ++k) mrg[(row * 4 + part) * 9 + k] = l[k];
    }
    __syncthreads();
    if (t < 128) {      // pair merge: (row, pr) merges lists 2pr, 2pr+1
        int r = t >> 1, pr = t & 1;
        const u64* LA = &mrg[(r * 4 + pr * 2) * 9];
        const u64* LB = LA + 9;
        int ia = 0, ib = 0;
        u64* Po = &mrg2[(r * 2 + pr) * 9];
        #pragma unroll
        for (int k = 0; k < 9; ++k) {
            u64 va = LA[ia], vb = LB[ib];
            bool ta = va < vb;
            Po[k] = ta ? va : vb;
            ia += ta; ib += !ta;
        }
    }
    __syncthreads();
    if (t < 64) {       // final in-block merge -> Part[row][mq]
        const u64* LA = &mrg2[(t * 2) * 9];
        const u64* LB = LA + 9;
        int ia = 0, ib = 0;
        u64* P = Part + (((long long)((b << 10) + q0 + t)) * 4 + mq) * 9;
        #pragma unroll
        for (int k = 0; k < 9; ++k) {
            u64 va = LA[ia], vb = LB[ib];
            bool ta = va < vb;
            P[k] = ta ? va : vb;
            ia += ta; ib += !ta;
        }
    }
}

// ---------------------------------------------------------------------------
// Merge the four m-quarter sorted lists -> final 9 neighbor indices per row.
// ---------------------------------------------------------------------------
__global__ __launch_bounds__(256)
void merge_final(const u64* __restrict__ Part, int* __restrict__ ix)
{
    int row = blockIdx.x * 256 + threadIdx.x;   // 0..16383
    const u64* L = Part + (long long)row * 36;
    int p0 = 0, p1 = 0, p2 = 0, p3 = 0;
    #pragma unroll
    for (int k = 0; k < 9; ++k) {
        u64 v0 = L[p0], v1 = L[9 + p1], v2 = L[18 + p2], v3 = L[27 + p3];
        u64 m01 = v0 < v1 ? v0 : v1;
        u64 m23 = v2 < v3 ? v2 : v3;
        u64 mn  = m01 < m23 ? m01 : m23;
        ix[row * 9 + k] = (int)(mn & 0xFFFFFFFFu);
        p0 += (mn == v0);
        p1 += (mn == v1) & (mn != v0);
        p2 += (mn == v2) & (mn != v0) & (mn != v1);
        p3 += (mn == v3) & (mn != v0) & (mn != v1) & (mn != v2);
    }
}

// ---------------------------------------------------------------------------
// build_Mt: Mt[b][n][2c]=bf16(Ft); Mt[b][n][2c+1]=bf16(max_k Ft[idx]-Ft)
// ---------------------------------------------------------------------------
__global__ __launch_bounds__(256)
void build_Mt(const float* __restrict__ Ft, const int* __restrict__ idx,
              short* __restrict__ Mt)
{
    int t = threadIdx.x;
    int wv = t >> 6, lane = t & 63;
    int n = blockIdx.x * 4 + wv;
    int b = blockIdx.y;
    int c0 = lane * 4;
    long long nb = (long long)(b << 10) + n;

    f4v f = *(const f4v*)(Ft + nb * C_ + c0);
    const int* id = idx + nb * 9;
    f4v mx = {-3.4e38f, -3.4e38f, -3.4e38f, -3.4e38f};
    #pragma unroll
    for (int k = 0; k < 9; ++k) {
        f4v g = *(const f4v*)(Ft + ((long long)(b << 10) + id[k]) * C_ + c0);
        mx[0] = fmaxf(mx[0], g[0]); mx[1] = fmaxf(mx[1], g[1]);
        mx[2] = fmaxf(mx[2], g[2]); mx[3] = fmaxf(mx[3], g[3]);
    }
    s8v m8;
    #pragma unroll
    for (int r = 0; r < 4; ++r) {
        m8[2 * r]     = (short)f2b(f[r]);
        m8[2 * r + 1] = (short)f2b(mx[r] - f[r]);
    }
    *(s8v*)(Mt + nb * (2 * C_) + 2 * c0) = m8;
}

// ---------------------------------------------------------------------------
// MFMA GEMM (known-good): acc[o][n] = sum_k A[o][k] * Bm[b][n][k]
// EPI 0: gelu(acc*s+t) -> bf16 Gt[b][n][Odim]
// EPI 1: acc*s+t + resid -> fp32 out[b][o][1024]
// ---------------------------------------------------------------------------
template<int EPI>
__global__ __launch_bounds__(256)
void mfma_gemm(const short* __restrict__ A, const short* __restrict__ Bm,
               void* __restrict__ Out, const float* __restrict__ scale,
               const float* __restrict__ bias, const void* __restrict__ resid,
               const int* __restrict__ flags, int K, int Odim)
{
    __shared__ short As[128][40];
    __shared__ short Bs[128][40];

    int t = threadIdx.x, b = blockIdx.z;
    int n0 = blockIdx.x * 128, o0 = blockIdx.y * 128;
    int wv = t >> 6, ln = t & 15, quad = (t >> 4) & 3;
    int wo = (wv & 1) * 64, wn = (wv >> 1) * 64;

    f4v acc[4][4];
    #pragma unroll
    for (int i = 0; i < 4; ++i)
        #pragma unroll
        for (int j = 0; j < 4; ++j) acc[i][j] = 0.f;

    const short* Ab = A + (long long)o0 * K;
    const short* Bb = Bm + ((long long)(b << 10) + n0) * K;

    for (int k0 = 0; k0 < K; k0 += 32) {
        __syncthreads();
        #pragma unroll
        for (int s = 0; s < 2; ++s) {
            int sid = t + s * 256;
            int row = sid >> 2, seg = sid & 3;
            *(s8v*)&As[row][seg * 8] = *(const s8v*)(Ab + (long long)row * K + k0 + seg * 8);
            *(s8v*)&Bs[row][seg * 8] = *(const s8v*)(Bb + (long long)row * K + k0 + seg * 8);
        }
        __syncthreads();
        s8v a[4], bf[4];
        #pragma unroll
        for (int i = 0; i < 4; ++i) a[i]  = *(s8v*)&As[wo + i * 16 + ln][quad * 8];
        #pragma unroll
        for (int j = 0; j < 4; ++j) bf[j] = *(s8v*)&Bs[wn + j * 16 + ln][quad * 8];
        #pragma unroll
        for (int i = 0; i < 4; ++i)
            #pragma unroll
            for (int j = 0; j < 4; ++j)
                acc[i][j] = __builtin_amdgcn_mfma_f32_16x16x32_bf16(a[i], bf[j], acc[i][j], 0, 0, 0);
    }

    int inf = flags[0];
    #pragma unroll
    for (int i = 0; i < 4; ++i) {
        int ob = o0 + wo + i * 16 + quad * 4;
        #pragma unroll
        for (int j = 0; j < 4; ++j) {
            int n = n0 + wn + j * 16 + ln;
            f4v v = acc[i][j];
            if (EPI == 0) {
                s4v g;
                #pragma unroll
                for (int r = 0; r < 4; ++r) {
                    float val = v[r] * scale[ob + r] + bias[ob + r];
                    val = 0.5f * val * (1.0f + erff(val * 0.70710678118654752f));
                    g[r] = (short)f2b(val);
                }
                *(s4v*)((short*)Out + ((long long)(b << 10) + n) * Odim + ob) = g;
            } else {
                #pragma unroll
                for (int r = 0; r < 4; ++r) {
                    int o = ob + r;
                    long long oi = ((long long)b * Odim + o) * N_ + n;
                    ((float*)Out)[oi] = v[r] * scale[o] + bias[o] + ldIn(resid, oi, inf);
                }
            }
        }
    }
}

// ---------------------------------------------------------------------------
extern "C" void kernel_launch(void* const* d_in, const int* in_sizes, int n_in,
                              void* d_out, int out_size, void* d_ws, size_t ws_size,
                              hipStream_t stream)
{
    const void* p[23];
    if (n_in >= 23 && in_sizes[0] != 4194304 && in_sizes[22] == 4194304) {
        const int amap[23] = {
            22, 13, 12, 1, 0, 2, 3,
            21, 20, 17, 16, 18, 19,
            5, 4, 6, 7,
            15, 14, 9, 8, 10, 11 };
        for (int i = 0; i < 23; ++i) p[i] = d_in[amap[i]];
    } else {
        for (int i = 0; i < 23; ++i) p[i] = d_in[i];
    }

    const void* x     = p[0];
    const void* fc1_w = p[1];
    const void* fc1_b = p[2];
    const void* bn1_g = p[3];
    const void* bn1_b = p[4];
    const void* bn1_m = p[5];
    const void* bn1_v = p[6];
    const void* gc_w  = p[7];
    const void* gc_b  = p[8];
    const void* gbn_g = p[9];
    const void* gbn_b = p[10];
    const void* gbn_m = p[11];
    const void* gbn_v = p[12];
    const void* bn2_g = p[13];
    const void* bn2_b = p[14];
    const void* bn2_m = p[15];
    const void* bn2_v = p[16];
    const void* fc2_w = p[17];
    const void* fc2_b = p[18];
    const void* bn3_g = p[19];
    const void* bn3_b = p[20];
    const void* bn3_m = p[21];
    const void* bn3_v = p[22];

    char* ws = (char*)d_ws;
    size_t off = 0;
    int*   flags = (int*)ws;
    float* s1 = (float*)(ws + 256);
    float* t1 = s1 + 256;
    float* s3 = t1 + 256;
    float* t3 = s3 + 256;
    float* Sg = t3 + 256;
    float* Tg = Sg + 512;
    off = 16384;
    int*   ixAll = (int*)(ws + off);  off += (size_t)B_ * N_ * 9 * 4;       // 576 KiB
    short* W1b   = (short*)(ws + off); off += (size_t)C_ * C_ * 2;          // 128 KiB
    short* Wgb   = (short*)(ws + off); off += (size_t)HID_ * 2 * C_ * 2;    // 512 KiB
    short* W2b   = (short*)(ws + off); off += (size_t)C_ * HID_ * 2;        // 256 KiB
    float* Ft    = (float*)(ws + off); off += (size_t)B_ * N_ * C_ * 4;     // 16 MiB
    short* Fhi   = (short*)(ws + off); off += (size_t)B_ * N_ * C_ * 2;     // 8 MiB
    short* Flo   = (short*)(ws + off); off += (size_t)B_ * N_ * C_ * 2;     // 8 MiB
    float* x2    = (float*)(ws + off); off += (size_t)B_ * N_ * 4;          // 64 KiB
    u64*   Part  = (u64*)  (ws + off); off += (size_t)B_ * N_ * 4 * 9 * 8;  // 4.5 MiB
    short* Mt    = (short*)(ws + off); off += (size_t)B_ * N_ * 2 * C_ * 2; // 16 MiB
    short* Gt    = (short*)(ws + off); off += (size_t)B_ * N_ * HID_ * 2;   // 16 MiB

    prep_kernel<<<1, 512, 0, stream>>>(x,
        fc1_b, bn1_g, bn1_b, bn1_m, bn1_v,
        gc_b, gbn_g, gbn_b, gbn_m, gbn_v,
        bn2_g, bn2_b, bn2_m, bn2_v,
        fc2_b, bn3_g, bn3_b, bn3_m, bn3_v,
        flags, s1, t1, Sg, Tg, s3, t3);

    cast_weights<<<1792, 256, 0, stream>>>(fc1_w, gc_w, fc2_w,
                                           W1b, Wgb, W2b, flags);

    fc1_valu<<<dim3(16, 4, B_), 256, 0, stream>>>(fc1_w, x, Ft, s1, t1, flags);

    prep_F<<<dim3(N_ / 4, B_), 256, 0, stream>>>(Ft, Fhi, Flo, x2);

    gram_topk<<<dim3(16, 4, 16), 256, 0, stream>>>(Fhi, Flo, x2, Part);
    merge_final<<<64, 256, 0, stream>>>(Part, ixAll);

    build_Mt<<<dim3(256, 16), 256, 0, stream>>>(Ft, ixAll, Mt);

    mfma_gemm<0><<<dim3(8, 4, 16), 256, 0, stream>>>(
        Wgb, Mt, Gt, Sg, Tg, nullptr, flags, 2 * C_, HID_);

    mfma_gemm<1><<<dim3(8, 2, 16), 256, 0, stream>>>(
        W2b, Gt, d_out, s3, t3, x, flags, HID_, C_);
}